// Round 15
// baseline (395.662 us; speedup 1.0000x reference)
//
#include <hip/hip_runtime.h>
#include <math.h>

#define NN 100000
#define NE 3200000
#define NEG 0.2f
#define NBKT 391   // ceil(NN/256) buckets of 256 nodes
#define TILE_E 2048     // R14: 8192->2048. kA1 was 53 us at 11% occupancy
                        // (391 blocks, latency-bound scatter, VALU 1.6%).
                        // 1563 blocks give 4x the waves to hide scatter
                        // latency. NE = 3125*1024 so any multiple of 1024
                        // divides the grid cleanly (tq = m>>10 handles it).
#define BCAP 12288      // padded bucket capacity (actual max ~8.5K for this graph)
#define K6_BLOCKS 3125  // 3125 blocks * 4 waves * 16 groups * 16 edges = 3.2M

typedef __attribute__((ext_vector_type(8))) short bf16x8;
typedef __attribute__((ext_vector_type(4))) float f32x4;

__device__ __forceinline__ float leaky(float v) { return v > 0.f ? v : NEG * v; }

__device__ __forceinline__ unsigned int f2bf(float f) {
    unsigned int u = __float_as_uint(f);
    return (u + 0x7fffu + ((u >> 16) & 1u)) >> 16;
}
__device__ __forceinline__ float bf2f(unsigned short h) {
    return __uint_as_float(((unsigned int)h) << 16);
}

// ---------------------------------------------------------------------------
// kA1: single-pass partition. dst row read ONCE (int4, kept in registers),
// LDS histogram -> global cursor reserve -> scatter (int4 src reads).
// R14 counters (at TILE_E=8192): 53 us, VALUBusy 1.6%, occupancy 11% --
// grid-limited TLP, scatter latency fully exposed. Fixed via TILE_E=2048.
__global__ void __launch_bounds__(256) kA1_part(const int* __restrict__ ei,
                                                int* __restrict__ bktcnt,
                                                int* __restrict__ ebuf) {
    __shared__ int cnt[NBKT];
    __shared__ int cur[NBKT];
    int t = threadIdx.x;
    for (int i = t; i < NBKT; i += 256) cnt[i] = 0;
    __syncthreads();
    int base = blockIdx.x * TILE_E;
    int m = min(TILE_E, NE - base);
    int tq = m >> 10;  // int4 loads per thread (1024 edges per unit)
    const int4* d4 = (const int4*)(ei + NE + base);
    const int4* s4 = (const int4*)(ei + base);
    int4 dd[8];
#pragma unroll
    for (int q = 0; q < 8; ++q) {
        if (q < tq) {
            int4 v = d4[q * 256 + t];
            dd[q] = v;
            atomicAdd(&cnt[v.x >> 8], 1);
            atomicAdd(&cnt[v.y >> 8], 1);
            atomicAdd(&cnt[v.z >> 8], 1);
            atomicAdd(&cnt[v.w >> 8], 1);
        }
    }
    __syncthreads();
    for (int i = t; i < NBKT; i += 256) {
        int c = cnt[i];
        cur[i] = c ? atomicAdd(&bktcnt[i], c) : 0;
    }
    __syncthreads();
#pragma unroll
    for (int q = 0; q < 8; ++q) {
        if (q < tq) {
            int4 sv = s4[q * 256 + t];
            int4 dv = dd[q];
            int b, p;
            b = dv.x >> 8; p = atomicAdd(&cur[b], 1);
            if (p < BCAP) ebuf[b * BCAP + p] = (sv.x << 8) | (dv.x & 255);
            b = dv.y >> 8; p = atomicAdd(&cur[b], 1);
            if (p < BCAP) ebuf[b * BCAP + p] = (sv.y << 8) | (dv.y & 255);
            b = dv.z >> 8; p = atomicAdd(&cur[b], 1);
            if (p < BCAP) ebuf[b * BCAP + p] = (sv.z << 8) | (dv.z & 255);
            b = dv.w >> 8; p = atomicAdd(&cur[b], 1);
            if (p < BCAP) ebuf[b * BCAP + p] = (sv.w << 8) | (dv.w & 255);
        }
    }
}

// ---------------------------------------------------------------------------
// kscan: exclusive scan of final bucket counts -> compact bucket offsets.
// Also computes the layer-1 attention constants c4 (absorbed k0).
__global__ void __launch_bounds__(512) kscan(const int* __restrict__ bktcnt,
                                             int* __restrict__ bktoff,
                                             int* __restrict__ rowst,
                                             const float* __restrict__ W1,
                                             const float* __restrict__ as1,
                                             const float* __restrict__ ad1,
                                             float* __restrict__ c4) {
    int t = threadIdx.x;
    if (t < 2) {  // k0: attention constants
        float cs = 0.f, cd = 0.f;
        for (int c = 0; c < 32; ++c) {
            float w = W1[t * 32 + c];
            cs += w * as1[t * 32 + c];
            cd += w * ad1[t * 32 + c];
        }
        c4[t] = cs;
        c4[2 + t] = cd;
    }
    __shared__ int sh[512];
    int v = (t < NBKT) ? min(bktcnt[t], BCAP) : 0;
    sh[t] = v;
    __syncthreads();
    for (int o = 1; o < 512; o <<= 1) {
        int add = (t >= o) ? sh[t - o] : 0;
        __syncthreads();
        sh[t] += add;
        __syncthreads();
    }
    if (t < NBKT) bktoff[t] = sh[t] - v;
    if (t == 511) {
        bktoff[NBKT] = sh[511];
        rowst[NN] = sh[511];
    }
}

// ---------------------------------------------------------------------------
// kB: fine counting sort within each bucket (256 nodes); int4 reads of the
// padded ebuf, emits compact rowstart + srcidx. (R12 fusion of k_agg1 into
// this kernel REFUTED: 391 blocks = 1.5 blocks/CU cannot hide the per-edge
// x[src]->exp->LDS-atomic chain; kB_sort went 95 us, occupancy 13%.)
__global__ void __launch_bounds__(256) kB_sort(const int* __restrict__ bktcnt,
                                               const int* __restrict__ bktoff,
                                               const int* __restrict__ ebuf,
                                               int* __restrict__ rowst,
                                               int* __restrict__ srcidx) {
    __shared__ int cnt[256];
    __shared__ int tmp[256];
    int b = blockIdx.x, t = threadIdx.x;
    int n = min(bktcnt[b], BCAP);
    int obase = bktoff[b];
    const int* ib = ebuf + b * BCAP;
    const int4* ib4 = (const int4*)ib;
    int nq = n >> 2;
    cnt[t] = 0;
    __syncthreads();
    for (int i = t; i < nq; i += 256) {
        int4 v = ib4[i];
        atomicAdd(&cnt[v.x & 255], 1);
        atomicAdd(&cnt[v.y & 255], 1);
        atomicAdd(&cnt[v.z & 255], 1);
        atomicAdd(&cnt[v.w & 255], 1);
    }
    for (int i = (nq << 2) + t; i < n; i += 256)
        atomicAdd(&cnt[ib[i] & 255], 1);
    __syncthreads();
    int v = cnt[t];
    tmp[t] = v;
    __syncthreads();
    for (int o = 1; o < 256; o <<= 1) {
        int add = (t >= o) ? tmp[t - o] : 0;
        __syncthreads();
        tmp[t] += add;
        __syncthreads();
    }
    int excl = tmp[t] - v;
    int node = (b << 8) + t;
    if (node < NN) rowst[node] = obase + excl;
    cnt[t] = obase + excl;  // cursor
    __syncthreads();
    for (int i = t; i < nq; i += 256) {
        int4 e4 = ib4[i];
        int p;
        p = atomicAdd(&cnt[e4.x & 255], 1); srcidx[p] = e4.x >> 8;
        p = atomicAdd(&cnt[e4.y & 255], 1); srcidx[p] = e4.y >> 8;
        p = atomicAdd(&cnt[e4.z & 255], 1); srcidx[p] = e4.z >> 8;
        p = atomicAdd(&cnt[e4.w & 255], 1); srcidx[p] = e4.w >> 8;
    }
    for (int i = (nq << 2) + t; i < n; i += 256) {
        int e = ib[i];
        int p = atomicAdd(&cnt[e & 255], 1);
        srcidx[p] = e >> 8;
    }
}

// ---------------------------------------------------------------------------
// Layer-1 aggregation (gather). 16 lanes per node; r2[n] = {T0/s0, T1/s1}.
// (Separate kernel on purpose: 6250 blocks give the TLP that hides the
// x-gather latency -- R12 proved this cannot live inside kB's 391 blocks.)
__global__ void __launch_bounds__(256) k_agg1(const int* __restrict__ rowstart,
                                              const int* __restrict__ srcidx,
                                              const float* __restrict__ x,
                                              const float* __restrict__ c4,
                                              float2* __restrict__ r2) {
    int gtid = blockIdx.x * blockDim.x + threadIdx.x;
    int n = gtid >> 4;
    int lane = gtid & 15;
    if (n >= NN) return;
    float c0 = c4[0], c1 = c4[1], c2 = c4[2], c3 = c4[3];
    float xd = x[n];
    float xdc2 = xd * c2, xdc3 = xd * c3;
    float s0 = 0.f, s1 = 0.f, t0 = 0.f, t1 = 0.f;
    int rs = rowstart[n], re = rowstart[n + 1];
    for (int i = rs + lane; i < re; i += 16) {
        float xs = x[__builtin_nontemporal_load(srcidx + i)];
        float ex0 = __expf(leaky(xs * c0 + xdc2));
        float ex1 = __expf(leaky(xs * c1 + xdc3));
        s0 += ex0;
        s1 += ex1;
        t0 += ex0 * xs;
        t1 += ex1 * xs;
    }
#pragma unroll
    for (int m = 8; m >= 1; m >>= 1) {
        s0 += __shfl_xor(s0, m, 16);
        s1 += __shfl_xor(s1, m, 16);
        t0 += __shfl_xor(t0, m, 16);
        t1 += __shfl_xor(t1, m, 16);
    }
    if (lane == 0) {
        float ex0 = __expf(leaky(xd * (c0 + c2)));
        float ex1 = __expf(leaky(xd * (c1 + c3)));
        s0 += ex0;
        s1 += ex1;
        t0 += ex0 * xd;
        t1 += ex1 * xd;
        r2[n] = make_float2(t0 / (s0 + 1e-16f), t1 / (s1 + 1e-16f));
    }
}

// ---------------------------------------------------------------------------
// k3: per-node layer-1 output -> h2 row (fp8 e4m3, 32 B/row -> 3.2 MB table,
// fits the 4 MB per-XCD L2) + layer-2 attention scalars (f32, full precision).
__global__ void __launch_bounds__(256) k3_node(const float2* __restrict__ r2,
                                               const float* __restrict__ W1,
                                               const float* __restrict__ b1,
                                               const float* __restrict__ W2,
                                               const float* __restrict__ as2,
                                               const float* __restrict__ ad2,
                                               unsigned int* __restrict__ h8,
                                               float2* __restrict__ a2) {
    int n = blockIdx.x * blockDim.x + threadIdx.x;
    if (n >= NN) return;
    float2 r = r2[n];
    float h2[32];
#pragma unroll
    for (int c = 0; c < 32; ++c) h2[c] = 0.f;
    for (int j = 0; j < 64; ++j) {
        float o = W1[j] * (j < 32 ? r.x : r.y) + b1[j];
        o = fmaxf(o, 0.f);
#pragma unroll
        for (int c = 0; c < 32; ++c) h2[c] += o * W2[j * 32 + c];
    }
    float asum = 0.f, adsum = 0.f;
#pragma unroll
    for (int c = 0; c < 32; ++c) {
        asum += h2[c] * as2[c];
        adsum += h2[c] * ad2[c];
    }
    a2[n] = make_float2(asum, adsum);
    unsigned int w[8];
#pragma unroll
    for (int q = 0; q < 8; ++q) {
        int v = __builtin_amdgcn_cvt_pk_fp8_f32(h2[q * 4 + 0], h2[q * 4 + 1], 0, false);
        v = __builtin_amdgcn_cvt_pk_fp8_f32(h2[q * 4 + 2], h2[q * 4 + 3], v, true);
        w[q] = (unsigned int)v;
    }
    uint4* hg = (uint4*)(h8 + (size_t)n * 8);
    hg[0] = make_uint4(w[0], w[1], w[2], w[3]);
    hg[1] = make_uint4(w[4], w[5], w[6], w[7]);
}

// ---------------------------------------------------------------------------
// Layer-2 aggregation (gather). 32 lanes per node, lane = channel.
// v2 (kept): latency-hiding restructure (LDS-staged off/ex broadcast,
// 32-deep MLP, padded batches -> no divergent tail). R14 counters: 52.8 us,
// VALUBusy 57%, occupancy 56% -- now issue-bound, acceptable.
__global__ void __launch_bounds__(256) k_agg2(const int* __restrict__ rowstart,
                                              const int* __restrict__ srcidx,
                                              const unsigned char* __restrict__ h8,
                                              const float2* __restrict__ a2,
                                              const float* __restrict__ b2,
                                              unsigned short* __restrict__ embq) {
    __shared__ int loff[256];
    __shared__ float lex[256];
    int tid = threadIdx.x;
    int gtid = blockIdx.x * 256 + tid;
    int n = gtid >> 5;
    int c = gtid & 31;
    if (n >= NN) return;
    int wbase = tid & ~31;  // this 32-lane group's LDS slot base
    float2 an = a2[n];
    float adn = an.y;
    float exn = __expf(leaky(an.x + adn));
    float u = exn * __builtin_amdgcn_cvt_f32_fp8(h8[((unsigned)n << 5) + c], 0);
    float lsum = 0.f;  // per-lane partial of sum(ex)
    int rs = rowstart[n], re = rowstart[n + 1];
    for (int base = rs; base < re; base += 32) {
        int cnt = re - base;
        int off = 0;
        float exj = 0.f;
        if (c < cnt) {
            int sjv = __builtin_nontemporal_load(srcidx + base + c);
            off = sjv << 5;
            float2 asrc = a2[sjv];  // issued early; latency overlapped below
            exj = __expf(leaky(asrc.x + adn));
            lsum += exj;
        }
        // stage offsets, then launch ALL 32 h8 loads (they only need srcidx)
        loff[tid] = off;
        asm volatile("s_waitcnt lgkmcnt(0)" ::: "memory");
        int4 ov[8];
#pragma unroll
        for (int q = 0; q < 8; ++q) ov[q] = ((const int4*)(loff + wbase))[q];
        unsigned int hb[32];
#pragma unroll
        for (int q = 0; q < 8; ++q) {
            hb[4 * q + 0] = h8[ov[q].x + c];
            hb[4 * q + 1] = h8[ov[q].y + c];
            hb[4 * q + 2] = h8[ov[q].z + c];
            hb[4 * q + 3] = h8[ov[q].w + c];
        }
        // stage ex (ready once the a2 gather + exp completes)
        lex[tid] = exj;
        asm volatile("s_waitcnt lgkmcnt(0)" ::: "memory");
#pragma unroll
        for (int q = 0; q < 8; ++q) {
            float4 ev = ((const float4*)(lex + wbase))[q];
            u += ev.x * __builtin_amdgcn_cvt_f32_fp8(hb[4 * q + 0], 0);
            u += ev.y * __builtin_amdgcn_cvt_f32_fp8(hb[4 * q + 1], 0);
            u += ev.z * __builtin_amdgcn_cvt_f32_fp8(hb[4 * q + 2], 0);
            u += ev.w * __builtin_amdgcn_cvt_f32_fp8(hb[4 * q + 3], 0);
        }
    }
#pragma unroll
    for (int m = 16; m >= 1; m >>= 1) lsum += __shfl_xor(lsum, m, 32);
    float ssum = lsum + exn;
    embq[((unsigned)n << 5) + c] = (unsigned short)f2bf(u / (ssum + 1e-16f) + b2[c]);
}

// ---------------------------------------------------------------------------
// k6: MFMA edge scorer.
// v6, re-merged to a single dispatch (the R14 split bought the kA1/k_agg2
// counters at ~17 us; visibility acquired, overhead reclaimed).
// Concurrency bracket complete (R5/R6/R11): v6 is argmax.
__global__ void __launch_bounds__(256) k6_mfma(const int* __restrict__ ei,
                                               const float* __restrict__ ea,
                                               const unsigned short* __restrict__ embq,
                                               const float* __restrict__ Wm1,
                                               const float* __restrict__ bm1,
                                               const float* __restrict__ Wm2,
                                               const float* __restrict__ bm2,
                                               const float* __restrict__ Wm3,
                                               const float* __restrict__ bm3,
                                               float* __restrict__ out) {
    __shared__ unsigned short ldsq[4][4 * 640];  // 4 waves x 4 tiles (bf16 ph1 out, f32 ph2 reuse)
    int tid = threadIdx.x;
    int wave = tid >> 6, lane = tid & 63;
    int m = lane & 15, quad = lane >> 4;
    unsigned short* wl = ldsq[wave];
    float* wz = (float*)wl;  // phase-2 alias of the same 5120-B wave zone

    // weight fragments; layer-1 tile t column m = channel 2m+t
    bf16x8 B1[3][2];
#pragma unroll
    for (int c = 0; c < 3; ++c) {
#pragma unroll
        for (int t = 0; t < 2; ++t) {
            bf16x8 v;
#pragma unroll
            for (int j = 0; j < 8; ++j) {
                int kk = c * 32 + quad * 8 + j;
                float w = (kk < 68) ? Wm1[kk * 32 + 2 * m + t] : 0.f;
                v[j] = (short)f2bf(w);
            }
            B1[c][t] = v;
        }
    }
    bf16x8 B2;
#pragma unroll
    for (int j = 0; j < 8; ++j)
        B2[j] = (short)f2bf(Wm2[(quad * 8 + j) * 16 + m]);
    float bl = bm1[2 * m], bh = bm1[2 * m + 1];
    float b2v = bm2[m], w3v = Wm3[m], b3 = bm3[0];

    int gw = blockIdx.x * 4 + wave;

    // double-buffered pipeline state
    int s2[2][4], d2[2][4];
    f32x4 ev2[2][4];
    bf16x8 A0[2][4], A1[2][4];

    auto LOADIDX = [&](int b, int ii) {
#pragma unroll
        for (int u = 0; u < 4; ++u) {
            int e = (gw * 16 + ii * 4) * 16 + u * 16 + m;
            s2[b][u] = __builtin_nontemporal_load(ei + e);
            d2[b][u] = __builtin_nontemporal_load(ei + NE + e);
            if (quad == 0)
                ev2[b][u] = __builtin_nontemporal_load((const f32x4*)ea + e);
        }
    };
    auto GATHER = [&](int b) {
#pragma unroll
        for (int u = 0; u < 4; ++u) {
            A0[b][u] = *(const bf16x8*)(embq + (((unsigned)s2[b][u] << 5) + quad * 8));
            A1[b][u] = *(const bf16x8*)(embq + (((unsigned)d2[b][u] << 5) + quad * 8));
        }
    };

    LOADIDX(0, 0);
    GATHER(0);
    LOADIDX(1, 1);

#pragma unroll
    for (int ii = 0; ii < 4; ++ii) {
        const int b = ii & 1;
        int eb0 = (gw * 16 + ii * 4) * 16;  // 64 consecutive edges
        // ---- phase 1: waits on GATHER(b) issued one iteration ago ----
#pragma unroll
        for (int u = 0; u < 4; ++u) {
            bf16x8 z = {0, 0, 0, 0, 0, 0, 0, 0};
            if (quad == 0) {
                f32x4 av = ev2[b][u];
                z[0] = (short)f2bf(av[0]);
                z[1] = (short)f2bf(av[1]);
                z[2] = (short)f2bf(av[2]);
                z[3] = (short)f2bf(av[3]);
            }
            f32x4 accL = {bl, bl, bl, bl};  // bias folded into acc init
            f32x4 accH = {bh, bh, bh, bh};
            accL = __builtin_amdgcn_mfma_f32_16x16x32_bf16(A0[b][u], B1[0][0], accL, 0, 0, 0);
            accH = __builtin_amdgcn_mfma_f32_16x16x32_bf16(A0[b][u], B1[0][1], accH, 0, 0, 0);
            accL = __builtin_amdgcn_mfma_f32_16x16x32_bf16(A1[b][u], B1[1][0], accL, 0, 0, 0);
            accH = __builtin_amdgcn_mfma_f32_16x16x32_bf16(A1[b][u], B1[1][1], accH, 0, 0, 0);
            accL = __builtin_amdgcn_mfma_f32_16x16x32_bf16(z, B1[2][0], accL, 0, 0, 0);
            accH = __builtin_amdgcn_mfma_f32_16x16x32_bf16(z, B1[2][1], accH, 0, 0, 0);
#pragma unroll
            for (int r = 0; r < 4; ++r) {
                int row = quad * 4 + r;
                unsigned int uL = __float_as_uint(fmaxf(accL[r], 0.f)) + 0x8000u;
                unsigned int uH = __float_as_uint(fmaxf(accH[r], 0.f)) + 0x8000u;
                unsigned int packed = __builtin_amdgcn_perm(uH, uL, 0x07060302);
                *(unsigned int*)(wl + u * 640 + row * 40 + 2 * m) = packed;
            }
        }
        // ---- issue next group's gathers / next-next index loads ----
        if (ii < 3) GATHER(b ^ 1);      // idx loaded 1-2 iterations ago
        if (ii < 2) LOADIDX(b, ii + 2); // buffer b's idx/frags just consumed
        asm volatile("s_waitcnt lgkmcnt(0)" ::: "memory");
        // ---- phase 2 (latency of the above loads hides under this) ----
#pragma unroll
        for (int u = 0; u < 4; ++u) {
            // read tile u (last use of its bf16 contents) ...
            bf16x8 aq = *(const bf16x8*)(wl + u * 640 + m * 40 + quad * 8);
            f32x4 accO = {b2v, b2v, b2v, b2v};  // layer-2 bias folded
            accO = __builtin_amdgcn_mfma_f32_16x16x32_bf16(aq, B2, accO, 0, 0, 0);
            // ... then overwrite tile u with the f32 edge x channel transpose
#pragma unroll
            for (int r = 0; r < 4; ++r) {
                int edge = u * 16 + quad * 4 + r;
                wz[edge * 20 + m] = fmaxf(accO[r], 0.f) * w3v;
            }
        }
        asm volatile("s_waitcnt lgkmcnt(0)" ::: "memory");
        // lane owns edge `lane`: sum 16 ch, sigmoid, coalesced store
        {
            f32x4 p0 = *(const f32x4*)(wz + lane * 20 + 0);
            f32x4 p1 = *(const f32x4*)(wz + lane * 20 + 4);
            f32x4 p2 = *(const f32x4*)(wz + lane * 20 + 8);
            f32x4 p3 = *(const f32x4*)(wz + lane * 20 + 12);
            float sum = ((p0[0] + p0[1]) + (p0[2] + p0[3])) +
                        ((p1[0] + p1[1]) + (p1[2] + p1[3])) +
                        ((p2[0] + p2[1]) + (p2[2] + p2[3])) +
                        ((p3[0] + p3[1]) + (p3[2] + p3[3]));
            float sc = 1.f / (1.f + __expf(-(sum + b3)));
            __builtin_nontemporal_store(sc, out + eb0 + lane);
        }
        asm volatile("" ::: "memory");
    }
}

// ---------------------------------------------------------------------------
extern "C" void kernel_launch(void* const* d_in, const int* in_sizes, int n_in,
                              void* d_out, int out_size, void* d_ws, size_t ws_size,
                              hipStream_t stream) {
    const float* x   = (const float*)d_in[0];
    const int* ei    = (const int*)d_in[1];
    const float* ea  = (const float*)d_in[2];
    const float* W1  = (const float*)d_in[3];
    const float* as1 = (const float*)d_in[4];
    const float* ad1 = (const float*)d_in[5];
    const float* b1  = (const float*)d_in[6];
    const float* W2  = (const float*)d_in[7];
    const float* as2 = (const float*)d_in[8];
    const float* ad2 = (const float*)d_in[9];
    const float* b2  = (const float*)d_in[10];
    const float* Wm1 = (const float*)d_in[11];
    const float* bm1 = (const float*)d_in[12];
    const float* Wm2 = (const float*)d_in[13];
    const float* bm2 = (const float*)d_in[14];
    const float* Wm3 = (const float*)d_in[15];
    const float* bm3 = (const float*)d_in[16];
    float* out = (float*)d_out;

    // workspace layout (bytes), total ~40.4 MB
    char* ws = (char*)d_ws;
    float* c4      = (float*)(ws + 0);          // 16 B
    int*   bktcnt  = (int*)  (ws + 256);        // NBKT*4 (cursor -> final counts)
    int*   bktoff  = (int*)  (ws + 2048);       // (NBKT+1)*4
    int*   rowst   = (int*)  (ws + 5632);       // (NN+1)*4
    float* r2      = (float*)(ws + 405760);     // NN*8
    float* a2      = (float*)(ws + 1205760);    // NN*8
    int*   ebufP   = (int*)  (ws + 2005760);    // NBKT*BCAP*4 = 19.2 MB (padded)
    int*   srcidx  = (int*)  (ws + 21224192);   // NE*4 = 12.8 MB
    unsigned char* h8    = (unsigned char*)ebufP;            // NN*32 fp8 = 3.2 MB (after kB)
    unsigned short* embq = (unsigned short*)(ws + 34024192); // NN*32*2 = 6.4 MB

    const int NB = (NN + 255) / 256;
    const int TB = (NE + TILE_E - 1) / TILE_E;  // 1563 at TILE_E=2048

    hipMemsetAsync(bktcnt, 0, NBKT * sizeof(int), stream);
    hipLaunchKernelGGL(kA1_part, dim3(TB), dim3(256), 0, stream, ei, bktcnt, ebufP);
    hipLaunchKernelGGL(kscan, dim3(1), dim3(512), 0, stream, bktcnt, bktoff, rowst,
                       W1, as1, ad1, c4);
    hipLaunchKernelGGL(kB_sort, dim3(NBKT), dim3(256), 0, stream, bktcnt, bktoff, ebufP,
                       rowst, srcidx);
    hipLaunchKernelGGL(k_agg1, dim3((NN * 16 + 255) / 256), dim3(256), 0, stream,
                       rowst, srcidx, x, c4, (float2*)r2);
    hipLaunchKernelGGL(k3_node, dim3(NB), dim3(256), 0, stream, (float2*)r2, W1, b1, W2,
                       as2, ad2, (unsigned int*)h8, (float2*)a2);
    hipLaunchKernelGGL(k_agg2, dim3((NN * 32 + 255) / 256), dim3(256), 0, stream,
                       rowst, srcidx, h8, (float2*)a2, b2, embq);
    hipLaunchKernelGGL(k6_mfma, dim3(K6_BLOCKS), dim3(256), 0, stream, ei, ea, embq,
                       Wm1, bm1, Wm2, bm2, Wm3, bm3, out);
}

// Round 16
// 345.425 us; speedup vs baseline: 1.1454x; 1.1454x over previous
//
#include <hip/hip_runtime.h>
#include <math.h>

#define NN 100000
#define NE 3200000
#define NEG 0.2f
#define NBKT 391   // ceil(NN/256) buckets of 256 nodes
#define TILE_E 8192     // R15 post-mortem: kA1 is WRITE-COALESCING bound, not
                        // TLP bound (2048: occ 55%, WRITE 81 MB, 84 us vs
                        // 8192: occ 11%, WRITE 38 MB, 53 us). Restored to 8192
                        // and fixed properly via LDS-staged coalesced flush.
#define BCAP 12288      // padded bucket capacity (actual max ~8.5K for this graph)
#define K6_BLOCKS 3125  // 3125 blocks * 4 waves * 16 groups * 16 edges = 3.2M

typedef __attribute__((ext_vector_type(8))) short bf16x8;
typedef __attribute__((ext_vector_type(4))) float f32x4;

__device__ __forceinline__ float leaky(float v) { return v > 0.f ? v : NEG * v; }

__device__ __forceinline__ unsigned int f2bf(float f) {
    unsigned int u = __float_as_uint(f);
    return (u + 0x7fffu + ((u >> 16) & 1u)) >> 16;
}
__device__ __forceinline__ float bf2f(unsigned short h) {
    return __uint_as_float(((unsigned int)h) << 16);
}

// ---------------------------------------------------------------------------
// kA1 v2: partition with COALESCED flush. The R15 counters showed the 4B
// scatter stores were the cost (each store its own 64B line transaction:
// WRITE_SIZE 3-6x the logical 12.8 MB). v2 stages the block's 8192 edges in
// LDS ordered by bucket (histogram -> scan -> LDS scatter), then flushes
// linearly: consecutive lanes write consecutive global addresses within each
// bucket's reserved run -> line-coalesced, fire-and-forget. LDS 57 KB.
__global__ void __launch_bounds__(256) kA1_part(const int* __restrict__ ei,
                                                int* __restrict__ bktcnt,
                                                int* __restrict__ ebuf) {
    __shared__ int cnt[NBKT];
    __shared__ int eofs[NBKT];   // local exclusive offset per bucket
    __shared__ int cur[NBKT];    // global base per bucket (this block's run)
    __shared__ int lcur[NBKT];   // local scatter cursor
    __shared__ int sh[512];      // scan workspace
    __shared__ int lstage[TILE_E];            // 32 KB staging, bucket-ordered
    __shared__ unsigned short lbkt[TILE_E];   // 16 KB bucket id per slot
    int t = threadIdx.x;
    for (int i = t; i < NBKT; i += 256) cnt[i] = 0;
    __syncthreads();
    int base = blockIdx.x * TILE_E;
    int m = min(TILE_E, NE - base);
    int tq = m >> 10;  // int4 loads per thread (8 full tiles, 5 last)
    const int4* d4 = (const int4*)(ei + NE + base);
    const int4* s4 = (const int4*)(ei + base);
    int4 dd[8];
#pragma unroll
    for (int q = 0; q < 8; ++q) {
        if (q < tq) {
            int4 v = d4[q * 256 + t];
            dd[q] = v;
            atomicAdd(&cnt[v.x >> 8], 1);
            atomicAdd(&cnt[v.y >> 8], 1);
            atomicAdd(&cnt[v.z >> 8], 1);
            atomicAdd(&cnt[v.w >> 8], 1);
        }
    }
    __syncthreads();
    // inclusive Hillis-Steele scan over 512-padded histogram (2 elems/thread)
    sh[t] = (t < NBKT) ? cnt[t] : 0;
    sh[t + 256] = (t + 256 < NBKT) ? cnt[t + 256] : 0;
    __syncthreads();
    for (int o = 1; o < 512; o <<= 1) {
        int a0 = (t >= o) ? sh[t - o] : 0;
        int a1 = ((t + 256) >= o) ? sh[t + 256 - o] : 0;
        __syncthreads();
        sh[t] += a0;
        sh[t + 256] += a1;
        __syncthreads();
    }
    // exclusive offsets, local cursors, global run reservation
    for (int i = t; i < NBKT; i += 256) {
        int c = cnt[i];
        int e = sh[i] - c;
        eofs[i] = e;
        lcur[i] = e;
        cur[i] = c ? atomicAdd(&bktcnt[i], c) : 0;
    }
    __syncthreads();
    // scatter into LDS staging (bucket-ordered)
#pragma unroll
    for (int q = 0; q < 8; ++q) {
        if (q < tq) {
            int4 sv = s4[q * 256 + t];
            int4 dv = dd[q];
            int b, p;
            b = dv.x >> 8; p = atomicAdd(&lcur[b], 1);
            lstage[p] = (sv.x << 8) | (dv.x & 255); lbkt[p] = (unsigned short)b;
            b = dv.y >> 8; p = atomicAdd(&lcur[b], 1);
            lstage[p] = (sv.y << 8) | (dv.y & 255); lbkt[p] = (unsigned short)b;
            b = dv.z >> 8; p = atomicAdd(&lcur[b], 1);
            lstage[p] = (sv.z << 8) | (dv.z & 255); lbkt[p] = (unsigned short)b;
            b = dv.w >> 8; p = atomicAdd(&lcur[b], 1);
            lstage[p] = (sv.w << 8) | (dv.w & 255); lbkt[p] = (unsigned short)b;
        }
    }
    __syncthreads();
    // coalesced flush: lane i writes slot i; consecutive lanes hit
    // consecutive global addresses inside each bucket's reserved run
    for (int i = t; i < m; i += 256) {
        int b = lbkt[i];
        int p = cur[b] + (i - eofs[b]);
        if (p < BCAP) ebuf[b * BCAP + p] = lstage[i];
    }
}

// ---------------------------------------------------------------------------
// kscan: exclusive scan of final bucket counts -> compact bucket offsets.
// Also computes the layer-1 attention constants c4 (absorbed k0).
__global__ void __launch_bounds__(512) kscan(const int* __restrict__ bktcnt,
                                             int* __restrict__ bktoff,
                                             int* __restrict__ rowst,
                                             const float* __restrict__ W1,
                                             const float* __restrict__ as1,
                                             const float* __restrict__ ad1,
                                             float* __restrict__ c4) {
    int t = threadIdx.x;
    if (t < 2) {  // k0: attention constants
        float cs = 0.f, cd = 0.f;
        for (int c = 0; c < 32; ++c) {
            float w = W1[t * 32 + c];
            cs += w * as1[t * 32 + c];
            cd += w * ad1[t * 32 + c];
        }
        c4[t] = cs;
        c4[2 + t] = cd;
    }
    __shared__ int sh[512];
    int v = (t < NBKT) ? min(bktcnt[t], BCAP) : 0;
    sh[t] = v;
    __syncthreads();
    for (int o = 1; o < 512; o <<= 1) {
        int add = (t >= o) ? sh[t - o] : 0;
        __syncthreads();
        sh[t] += add;
        __syncthreads();
    }
    if (t < NBKT) bktoff[t] = sh[t] - v;
    if (t == 511) {
        bktoff[NBKT] = sh[511];
        rowst[NN] = sh[511];
    }
}

// ---------------------------------------------------------------------------
// kB: fine counting sort within each bucket (256 nodes); int4 reads of the
// padded ebuf, emits compact rowstart + srcidx. (R12 fusion of k_agg1 into
// this kernel REFUTED: 391 blocks = 1.5 blocks/CU cannot hide the per-edge
// x[src]->exp->LDS-atomic chain; kB_sort went 95 us, occupancy 13%.)
__global__ void __launch_bounds__(256) kB_sort(const int* __restrict__ bktcnt,
                                               const int* __restrict__ bktoff,
                                               const int* __restrict__ ebuf,
                                               int* __restrict__ rowst,
                                               int* __restrict__ srcidx) {
    __shared__ int cnt[256];
    __shared__ int tmp[256];
    int b = blockIdx.x, t = threadIdx.x;
    int n = min(bktcnt[b], BCAP);
    int obase = bktoff[b];
    const int* ib = ebuf + b * BCAP;
    const int4* ib4 = (const int4*)ib;
    int nq = n >> 2;
    cnt[t] = 0;
    __syncthreads();
    for (int i = t; i < nq; i += 256) {
        int4 v = ib4[i];
        atomicAdd(&cnt[v.x & 255], 1);
        atomicAdd(&cnt[v.y & 255], 1);
        atomicAdd(&cnt[v.z & 255], 1);
        atomicAdd(&cnt[v.w & 255], 1);
    }
    for (int i = (nq << 2) + t; i < n; i += 256)
        atomicAdd(&cnt[ib[i] & 255], 1);
    __syncthreads();
    int v = cnt[t];
    tmp[t] = v;
    __syncthreads();
    for (int o = 1; o < 256; o <<= 1) {
        int add = (t >= o) ? tmp[t - o] : 0;
        __syncthreads();
        tmp[t] += add;
        __syncthreads();
    }
    int excl = tmp[t] - v;
    int node = (b << 8) + t;
    if (node < NN) rowst[node] = obase + excl;
    cnt[t] = obase + excl;  // cursor
    __syncthreads();
    for (int i = t; i < nq; i += 256) {
        int4 e4 = ib4[i];
        int p;
        p = atomicAdd(&cnt[e4.x & 255], 1); srcidx[p] = e4.x >> 8;
        p = atomicAdd(&cnt[e4.y & 255], 1); srcidx[p] = e4.y >> 8;
        p = atomicAdd(&cnt[e4.z & 255], 1); srcidx[p] = e4.z >> 8;
        p = atomicAdd(&cnt[e4.w & 255], 1); srcidx[p] = e4.w >> 8;
    }
    for (int i = (nq << 2) + t; i < n; i += 256) {
        int e = ib[i];
        int p = atomicAdd(&cnt[e & 255], 1);
        srcidx[p] = e >> 8;
    }
}

// ---------------------------------------------------------------------------
// Layer-1 aggregation (gather). 16 lanes per node; r2[n] = {T0/s0, T1/s1}.
// (Separate kernel on purpose: 6250 blocks give the TLP that hides the
// x-gather latency -- R12 proved this cannot live inside kB's 391 blocks.)
__global__ void __launch_bounds__(256) k_agg1(const int* __restrict__ rowstart,
                                              const int* __restrict__ srcidx,
                                              const float* __restrict__ x,
                                              const float* __restrict__ c4,
                                              float2* __restrict__ r2) {
    int gtid = blockIdx.x * blockDim.x + threadIdx.x;
    int n = gtid >> 4;
    int lane = gtid & 15;
    if (n >= NN) return;
    float c0 = c4[0], c1 = c4[1], c2 = c4[2], c3 = c4[3];
    float xd = x[n];
    float xdc2 = xd * c2, xdc3 = xd * c3;
    float s0 = 0.f, s1 = 0.f, t0 = 0.f, t1 = 0.f;
    int rs = rowstart[n], re = rowstart[n + 1];
    for (int i = rs + lane; i < re; i += 16) {
        float xs = x[__builtin_nontemporal_load(srcidx + i)];
        float ex0 = __expf(leaky(xs * c0 + xdc2));
        float ex1 = __expf(leaky(xs * c1 + xdc3));
        s0 += ex0;
        s1 += ex1;
        t0 += ex0 * xs;
        t1 += ex1 * xs;
    }
#pragma unroll
    for (int m = 8; m >= 1; m >>= 1) {
        s0 += __shfl_xor(s0, m, 16);
        s1 += __shfl_xor(s1, m, 16);
        t0 += __shfl_xor(t0, m, 16);
        t1 += __shfl_xor(t1, m, 16);
    }
    if (lane == 0) {
        float ex0 = __expf(leaky(xd * (c0 + c2)));
        float ex1 = __expf(leaky(xd * (c1 + c3)));
        s0 += ex0;
        s1 += ex1;
        t0 += ex0 * xd;
        t1 += ex1 * xd;
        r2[n] = make_float2(t0 / (s0 + 1e-16f), t1 / (s1 + 1e-16f));
    }
}

// ---------------------------------------------------------------------------
// k3: per-node layer-1 output -> h2 row (fp8 e4m3, 32 B/row -> 3.2 MB table,
// fits the 4 MB per-XCD L2) + layer-2 attention scalars (f32, full precision).
__global__ void __launch_bounds__(256) k3_node(const float2* __restrict__ r2,
                                               const float* __restrict__ W1,
                                               const float* __restrict__ b1,
                                               const float* __restrict__ W2,
                                               const float* __restrict__ as2,
                                               const float* __restrict__ ad2,
                                               unsigned int* __restrict__ h8,
                                               float2* __restrict__ a2) {
    int n = blockIdx.x * blockDim.x + threadIdx.x;
    if (n >= NN) return;
    float2 r = r2[n];
    float h2[32];
#pragma unroll
    for (int c = 0; c < 32; ++c) h2[c] = 0.f;
    for (int j = 0; j < 64; ++j) {
        float o = W1[j] * (j < 32 ? r.x : r.y) + b1[j];
        o = fmaxf(o, 0.f);
#pragma unroll
        for (int c = 0; c < 32; ++c) h2[c] += o * W2[j * 32 + c];
    }
    float asum = 0.f, adsum = 0.f;
#pragma unroll
    for (int c = 0; c < 32; ++c) {
        asum += h2[c] * as2[c];
        adsum += h2[c] * ad2[c];
    }
    a2[n] = make_float2(asum, adsum);
    unsigned int w[8];
#pragma unroll
    for (int q = 0; q < 8; ++q) {
        int v = __builtin_amdgcn_cvt_pk_fp8_f32(h2[q * 4 + 0], h2[q * 4 + 1], 0, false);
        v = __builtin_amdgcn_cvt_pk_fp8_f32(h2[q * 4 + 2], h2[q * 4 + 3], v, true);
        w[q] = (unsigned int)v;
    }
    uint4* hg = (uint4*)(h8 + (size_t)n * 8);
    hg[0] = make_uint4(w[0], w[1], w[2], w[3]);
    hg[1] = make_uint4(w[4], w[5], w[6], w[7]);
}

// ---------------------------------------------------------------------------
// Layer-2 aggregation (gather). 32 lanes per node, lane = channel.
// v2 (kept): latency-hiding restructure (LDS-staged off/ex broadcast,
// 32-deep MLP, padded batches -> no divergent tail). R14 counters: 52.8 us,
// VALUBusy 57%, occupancy 56% -- now issue-bound, acceptable.
__global__ void __launch_bounds__(256) k_agg2(const int* __restrict__ rowstart,
                                              const int* __restrict__ srcidx,
                                              const unsigned char* __restrict__ h8,
                                              const float2* __restrict__ a2,
                                              const float* __restrict__ b2,
                                              unsigned short* __restrict__ embq) {
    __shared__ int loff[256];
    __shared__ float lex[256];
    int tid = threadIdx.x;
    int gtid = blockIdx.x * 256 + tid;
    int n = gtid >> 5;
    int c = gtid & 31;
    if (n >= NN) return;
    int wbase = tid & ~31;  // this 32-lane group's LDS slot base
    float2 an = a2[n];
    float adn = an.y;
    float exn = __expf(leaky(an.x + adn));
    float u = exn * __builtin_amdgcn_cvt_f32_fp8(h8[((unsigned)n << 5) + c], 0);
    float lsum = 0.f;  // per-lane partial of sum(ex)
    int rs = rowstart[n], re = rowstart[n + 1];
    for (int base = rs; base < re; base += 32) {
        int cnt = re - base;
        int off = 0;
        float exj = 0.f;
        if (c < cnt) {
            int sjv = __builtin_nontemporal_load(srcidx + base + c);
            off = sjv << 5;
            float2 asrc = a2[sjv];  // issued early; latency overlapped below
            exj = __expf(leaky(asrc.x + adn));
            lsum += exj;
        }
        // stage offsets, then launch ALL 32 h8 loads (they only need srcidx)
        loff[tid] = off;
        asm volatile("s_waitcnt lgkmcnt(0)" ::: "memory");
        int4 ov[8];
#pragma unroll
        for (int q = 0; q < 8; ++q) ov[q] = ((const int4*)(loff + wbase))[q];
        unsigned int hb[32];
#pragma unroll
        for (int q = 0; q < 8; ++q) {
            hb[4 * q + 0] = h8[ov[q].x + c];
            hb[4 * q + 1] = h8[ov[q].y + c];
            hb[4 * q + 2] = h8[ov[q].z + c];
            hb[4 * q + 3] = h8[ov[q].w + c];
        }
        // stage ex (ready once the a2 gather + exp completes)
        lex[tid] = exj;
        asm volatile("s_waitcnt lgkmcnt(0)" ::: "memory");
#pragma unroll
        for (int q = 0; q < 8; ++q) {
            float4 ev = ((const float4*)(lex + wbase))[q];
            u += ev.x * __builtin_amdgcn_cvt_f32_fp8(hb[4 * q + 0], 0);
            u += ev.y * __builtin_amdgcn_cvt_f32_fp8(hb[4 * q + 1], 0);
            u += ev.z * __builtin_amdgcn_cvt_f32_fp8(hb[4 * q + 2], 0);
            u += ev.w * __builtin_amdgcn_cvt_f32_fp8(hb[4 * q + 3], 0);
        }
    }
#pragma unroll
    for (int m = 16; m >= 1; m >>= 1) lsum += __shfl_xor(lsum, m, 32);
    float ssum = lsum + exn;
    embq[((unsigned)n << 5) + c] = (unsigned short)f2bf(u / (ssum + 1e-16f) + b2[c]);
}

// ---------------------------------------------------------------------------
// k6: MFMA edge scorer.
// v6 (best measured: 78.4 us), single dispatch. Concurrency bracket complete
// (R5/R6/R11): v6 is argmax; remaining levers are traffic-shaped only.
__global__ void __launch_bounds__(256) k6_mfma(const int* __restrict__ ei,
                                               const float* __restrict__ ea,
                                               const unsigned short* __restrict__ embq,
                                               const float* __restrict__ Wm1,
                                               const float* __restrict__ bm1,
                                               const float* __restrict__ Wm2,
                                               const float* __restrict__ bm2,
                                               const float* __restrict__ Wm3,
                                               const float* __restrict__ bm3,
                                               float* __restrict__ out) {
    __shared__ unsigned short ldsq[4][4 * 640];  // 4 waves x 4 tiles (bf16 ph1 out, f32 ph2 reuse)
    int tid = threadIdx.x;
    int wave = tid >> 6, lane = tid & 63;
    int m = lane & 15, quad = lane >> 4;
    unsigned short* wl = ldsq[wave];
    float* wz = (float*)wl;  // phase-2 alias of the same 5120-B wave zone

    // weight fragments; layer-1 tile t column m = channel 2m+t
    bf16x8 B1[3][2];
#pragma unroll
    for (int c = 0; c < 3; ++c) {
#pragma unroll
        for (int t = 0; t < 2; ++t) {
            bf16x8 v;
#pragma unroll
            for (int j = 0; j < 8; ++j) {
                int kk = c * 32 + quad * 8 + j;
                float w = (kk < 68) ? Wm1[kk * 32 + 2 * m + t] : 0.f;
                v[j] = (short)f2bf(w);
            }
            B1[c][t] = v;
        }
    }
    bf16x8 B2;
#pragma unroll
    for (int j = 0; j < 8; ++j)
        B2[j] = (short)f2bf(Wm2[(quad * 8 + j) * 16 + m]);
    float bl = bm1[2 * m], bh = bm1[2 * m + 1];
    float b2v = bm2[m], w3v = Wm3[m], b3 = bm3[0];

    int gw = blockIdx.x * 4 + wave;

    // double-buffered pipeline state
    int s2[2][4], d2[2][4];
    f32x4 ev2[2][4];
    bf16x8 A0[2][4], A1[2][4];

    auto LOADIDX = [&](int b, int ii) {
#pragma unroll
        for (int u = 0; u < 4; ++u) {
            int e = (gw * 16 + ii * 4) * 16 + u * 16 + m;
            s2[b][u] = __builtin_nontemporal_load(ei + e);
            d2[b][u] = __builtin_nontemporal_load(ei + NE + e);
            if (quad == 0)
                ev2[b][u] = __builtin_nontemporal_load((const f32x4*)ea + e);
        }
    };
    auto GATHER = [&](int b) {
#pragma unroll
        for (int u = 0; u < 4; ++u) {
            A0[b][u] = *(const bf16x8*)(embq + (((unsigned)s2[b][u] << 5) + quad * 8));
            A1[b][u] = *(const bf16x8*)(embq + (((unsigned)d2[b][u] << 5) + quad * 8));
        }
    };

    LOADIDX(0, 0);
    GATHER(0);
    LOADIDX(1, 1);

#pragma unroll
    for (int ii = 0; ii < 4; ++ii) {
        const int b = ii & 1;
        int eb0 = (gw * 16 + ii * 4) * 16;  // 64 consecutive edges
        // ---- phase 1: waits on GATHER(b) issued one iteration ago ----
#pragma unroll
        for (int u = 0; u < 4; ++u) {
            bf16x8 z = {0, 0, 0, 0, 0, 0, 0, 0};
            if (quad == 0) {
                f32x4 av = ev2[b][u];
                z[0] = (short)f2bf(av[0]);
                z[1] = (short)f2bf(av[1]);
                z[2] = (short)f2bf(av[2]);
                z[3] = (short)f2bf(av[3]);
            }
            f32x4 accL = {bl, bl, bl, bl};  // bias folded into acc init
            f32x4 accH = {bh, bh, bh, bh};
            accL = __builtin_amdgcn_mfma_f32_16x16x32_bf16(A0[b][u], B1[0][0], accL, 0, 0, 0);
            accH = __builtin_amdgcn_mfma_f32_16x16x32_bf16(A0[b][u], B1[0][1], accH, 0, 0, 0);
            accL = __builtin_amdgcn_mfma_f32_16x16x32_bf16(A1[b][u], B1[1][0], accL, 0, 0, 0);
            accH = __builtin_amdgcn_mfma_f32_16x16x32_bf16(A1[b][u], B1[1][1], accH, 0, 0, 0);
            accL = __builtin_amdgcn_mfma_f32_16x16x32_bf16(z, B1[2][0], accL, 0, 0, 0);
            accH = __builtin_amdgcn_mfma_f32_16x16x32_bf16(z, B1[2][1], accH, 0, 0, 0);
#pragma unroll
            for (int r = 0; r < 4; ++r) {
                int row = quad * 4 + r;
                unsigned int uL = __float_as_uint(fmaxf(accL[r], 0.f)) + 0x8000u;
                unsigned int uH = __float_as_uint(fmaxf(accH[r], 0.f)) + 0x8000u;
                unsigned int packed = __builtin_amdgcn_perm(uH, uL, 0x07060302);
                *(unsigned int*)(wl + u * 640 + row * 40 + 2 * m) = packed;
            }
        }
        // ---- issue next group's gathers / next-next index loads ----
        if (ii < 3) GATHER(b ^ 1);      // idx loaded 1-2 iterations ago
        if (ii < 2) LOADIDX(b, ii + 2); // buffer b's idx/frags just consumed
        asm volatile("s_waitcnt lgkmcnt(0)" ::: "memory");
        // ---- phase 2 (latency of the above loads hides under this) ----
#pragma unroll
        for (int u = 0; u < 4; ++u) {
            // read tile u (last use of its bf16 contents) ...
            bf16x8 aq = *(const bf16x8*)(wl + u * 640 + m * 40 + quad * 8);
            f32x4 accO = {b2v, b2v, b2v, b2v};  // layer-2 bias folded
            accO = __builtin_amdgcn_mfma_f32_16x16x32_bf16(aq, B2, accO, 0, 0, 0);
            // ... then overwrite tile u with the f32 edge x channel transpose
#pragma unroll
            for (int r = 0; r < 4; ++r) {
                int edge = u * 16 + quad * 4 + r;
                wz[edge * 20 + m] = fmaxf(accO[r], 0.f) * w3v;
            }
        }
        asm volatile("s_waitcnt lgkmcnt(0)" ::: "memory");
        // lane owns edge `lane`: sum 16 ch, sigmoid, coalesced store
        {
            f32x4 p0 = *(const f32x4*)(wz + lane * 20 + 0);
            f32x4 p1 = *(const f32x4*)(wz + lane * 20 + 4);
            f32x4 p2 = *(const f32x4*)(wz + lane * 20 + 8);
            f32x4 p3 = *(const f32x4*)(wz + lane * 20 + 12);
            float sum = ((p0[0] + p0[1]) + (p0[2] + p0[3])) +
                        ((p1[0] + p1[1]) + (p1[2] + p1[3])) +
                        ((p2[0] + p2[1]) + (p2[2] + p2[3])) +
                        ((p3[0] + p3[1]) + (p3[2] + p3[3]));
            float sc = 1.f / (1.f + __expf(-(sum + b3)));
            __builtin_nontemporal_store(sc, out + eb0 + lane);
        }
        asm volatile("" ::: "memory");
    }
}

// ---------------------------------------------------------------------------
extern "C" void kernel_launch(void* const* d_in, const int* in_sizes, int n_in,
                              void* d_out, int out_size, void* d_ws, size_t ws_size,
                              hipStream_t stream) {
    const float* x   = (const float*)d_in[0];
    const int* ei    = (const int*)d_in[1];
    const float* ea  = (const float*)d_in[2];
    const float* W1  = (const float*)d_in[3];
    const float* as1 = (const float*)d_in[4];
    const float* ad1 = (const float*)d_in[5];
    const float* b1  = (const float*)d_in[6];
    const float* W2  = (const float*)d_in[7];
    const float* as2 = (const float*)d_in[8];
    const float* ad2 = (const float*)d_in[9];
    const float* b2  = (const float*)d_in[10];
    const float* Wm1 = (const float*)d_in[11];
    const float* bm1 = (const float*)d_in[12];
    const float* Wm2 = (const float*)d_in[13];
    const float* bm2 = (const float*)d_in[14];
    const float* Wm3 = (const float*)d_in[15];
    const float* bm3 = (const float*)d_in[16];
    float* out = (float*)d_out;

    // workspace layout (bytes), total ~40.4 MB
    char* ws = (char*)d_ws;
    float* c4      = (float*)(ws + 0);          // 16 B
    int*   bktcnt  = (int*)  (ws + 256);        // NBKT*4 (cursor -> final counts)
    int*   bktoff  = (int*)  (ws + 2048);       // (NBKT+1)*4
    int*   rowst   = (int*)  (ws + 5632);       // (NN+1)*4
    float* r2      = (float*)(ws + 405760);     // NN*8
    float* a2      = (float*)(ws + 1205760);    // NN*8
    int*   ebufP   = (int*)  (ws + 2005760);    // NBKT*BCAP*4 = 19.2 MB (padded)
    int*   srcidx  = (int*)  (ws + 21224192);   // NE*4 = 12.8 MB
    unsigned char* h8    = (unsigned char*)ebufP;            // NN*32 fp8 = 3.2 MB (after kB)
    unsigned short* embq = (unsigned short*)(ws + 34024192); // NN*32*2 = 6.4 MB

    const int NB = (NN + 255) / 256;
    const int TB = (NE + TILE_E - 1) / TILE_E;  // 391 at TILE_E=8192

    hipMemsetAsync(bktcnt, 0, NBKT * sizeof(int), stream);
    hipLaunchKernelGGL(kA1_part, dim3(TB), dim3(256), 0, stream, ei, bktcnt, ebufP);
    hipLaunchKernelGGL(kscan, dim3(1), dim3(512), 0, stream, bktcnt, bktoff, rowst,
                       W1, as1, ad1, c4);
    hipLaunchKernelGGL(kB_sort, dim3(NBKT), dim3(256), 0, stream, bktcnt, bktoff, ebufP,
                       rowst, srcidx);
    hipLaunchKernelGGL(k_agg1, dim3((NN * 16 + 255) / 256), dim3(256), 0, stream,
                       rowst, srcidx, x, c4, (float2*)r2);
    hipLaunchKernelGGL(k3_node, dim3(NB), dim3(256), 0, stream, (float2*)r2, W1, b1, W2,
                       as2, ad2, (unsigned int*)h8, (float2*)a2);
    hipLaunchKernelGGL(k_agg2, dim3((NN * 32 + 255) / 256), dim3(256), 0, stream,
                       rowst, srcidx, h8, (float2*)a2, b2, embq);
    hipLaunchKernelGGL(k6_mfma, dim3(K6_BLOCKS), dim3(256), 0, stream, ei, ea, embq,
                       Wm1, bm1, Wm2, bm2, Wm3, bm3, out);
}

// Round 17
// 333.687 us; speedup vs baseline: 1.1857x; 1.0352x over previous
//
#include <hip/hip_runtime.h>
#include <math.h>

#define NN 100000
#define NE 3200000
#define NEG 0.2f
#define NBKT 391   // ceil(NN/256) buckets of 256 nodes
#define TILE_E 8192     // kA1 v2: write-coalescing fixed via LDS-staged flush (R16: -30+ us)
#define BCAP 12288      // padded bucket capacity (actual max ~8.5K for this graph)
#define K6_BLOCKS 3125  // 3125 blocks * 4 waves * 16 groups * 16 edges = 3.2M

typedef __attribute__((ext_vector_type(8))) short bf16x8;
typedef __attribute__((ext_vector_type(4))) float f32x4;

__device__ __forceinline__ float leaky(float v) { return v > 0.f ? v : NEG * v; }

__device__ __forceinline__ unsigned int f2bf(float f) {
    unsigned int u = __float_as_uint(f);
    return (u + 0x7fffu + ((u >> 16) & 1u)) >> 16;
}
__device__ __forceinline__ float bf2f(unsigned short h) {
    return __uint_as_float(((unsigned int)h) << 16);
}

// ---------------------------------------------------------------------------
// kA1 v2: partition with COALESCED flush (R16-verified win: kA1 84.6 -> <15).
// Stages the block's 8192 edges in LDS ordered by bucket (histogram -> scan
// -> LDS scatter), then flushes linearly: consecutive lanes write consecutive
// global addresses within each bucket's reserved run. LDS 57 KB.
__global__ void __launch_bounds__(256) kA1_part(const int* __restrict__ ei,
                                                int* __restrict__ bktcnt,
                                                int* __restrict__ ebuf) {
    __shared__ int cnt[NBKT];
    __shared__ int eofs[NBKT];   // local exclusive offset per bucket
    __shared__ int cur[NBKT];    // global base per bucket (this block's run)
    __shared__ int lcur[NBKT];   // local scatter cursor
    __shared__ int sh[512];      // scan workspace
    __shared__ int lstage[TILE_E];            // 32 KB staging, bucket-ordered
    __shared__ unsigned short lbkt[TILE_E];   // 16 KB bucket id per slot
    int t = threadIdx.x;
    for (int i = t; i < NBKT; i += 256) cnt[i] = 0;
    __syncthreads();
    int base = blockIdx.x * TILE_E;
    int m = min(TILE_E, NE - base);
    int tq = m >> 10;  // int4 loads per thread (8 full tiles, 5 last)
    const int4* d4 = (const int4*)(ei + NE + base);
    const int4* s4 = (const int4*)(ei + base);
    int4 dd[8];
#pragma unroll
    for (int q = 0; q < 8; ++q) {
        if (q < tq) {
            int4 v = d4[q * 256 + t];
            dd[q] = v;
            atomicAdd(&cnt[v.x >> 8], 1);
            atomicAdd(&cnt[v.y >> 8], 1);
            atomicAdd(&cnt[v.z >> 8], 1);
            atomicAdd(&cnt[v.w >> 8], 1);
        }
    }
    __syncthreads();
    // inclusive Hillis-Steele scan over 512-padded histogram (2 elems/thread)
    sh[t] = (t < NBKT) ? cnt[t] : 0;
    sh[t + 256] = (t + 256 < NBKT) ? cnt[t + 256] : 0;
    __syncthreads();
    for (int o = 1; o < 512; o <<= 1) {
        int a0 = (t >= o) ? sh[t - o] : 0;
        int a1 = ((t + 256) >= o) ? sh[t + 256 - o] : 0;
        __syncthreads();
        sh[t] += a0;
        sh[t + 256] += a1;
        __syncthreads();
    }
    // exclusive offsets, local cursors, global run reservation
    for (int i = t; i < NBKT; i += 256) {
        int c = cnt[i];
        int e = sh[i] - c;
        eofs[i] = e;
        lcur[i] = e;
        cur[i] = c ? atomicAdd(&bktcnt[i], c) : 0;
    }
    __syncthreads();
    // scatter into LDS staging (bucket-ordered)
#pragma unroll
    for (int q = 0; q < 8; ++q) {
        if (q < tq) {
            int4 sv = s4[q * 256 + t];
            int4 dv = dd[q];
            int b, p;
            b = dv.x >> 8; p = atomicAdd(&lcur[b], 1);
            lstage[p] = (sv.x << 8) | (dv.x & 255); lbkt[p] = (unsigned short)b;
            b = dv.y >> 8; p = atomicAdd(&lcur[b], 1);
            lstage[p] = (sv.y << 8) | (dv.y & 255); lbkt[p] = (unsigned short)b;
            b = dv.z >> 8; p = atomicAdd(&lcur[b], 1);
            lstage[p] = (sv.z << 8) | (dv.z & 255); lbkt[p] = (unsigned short)b;
            b = dv.w >> 8; p = atomicAdd(&lcur[b], 1);
            lstage[p] = (sv.w << 8) | (dv.w & 255); lbkt[p] = (unsigned short)b;
        }
    }
    __syncthreads();
    // coalesced flush: lane i writes slot i; consecutive lanes hit
    // consecutive global addresses inside each bucket's reserved run
    for (int i = t; i < m; i += 256) {
        int b = lbkt[i];
        int p = cur[b] + (i - eofs[b]);
        if (p < BCAP) ebuf[b * BCAP + p] = lstage[i];
    }
}

// ---------------------------------------------------------------------------
// kscan: exclusive scan of final bucket counts -> compact bucket offsets.
// Also computes the layer-1 attention constants c4 (absorbed k0).
__global__ void __launch_bounds__(512) kscan(const int* __restrict__ bktcnt,
                                             int* __restrict__ bktoff,
                                             int* __restrict__ rowst,
                                             const float* __restrict__ W1,
                                             const float* __restrict__ as1,
                                             const float* __restrict__ ad1,
                                             float* __restrict__ c4) {
    int t = threadIdx.x;
    if (t < 2) {  // k0: attention constants
        float cs = 0.f, cd = 0.f;
        for (int c = 0; c < 32; ++c) {
            float w = W1[t * 32 + c];
            cs += w * as1[t * 32 + c];
            cd += w * ad1[t * 32 + c];
        }
        c4[t] = cs;
        c4[2 + t] = cd;
    }
    __shared__ int sh[512];
    int v = (t < NBKT) ? min(bktcnt[t], BCAP) : 0;
    sh[t] = v;
    __syncthreads();
    for (int o = 1; o < 512; o <<= 1) {
        int add = (t >= o) ? sh[t - o] : 0;
        __syncthreads();
        sh[t] += add;
        __syncthreads();
    }
    if (t < NBKT) bktoff[t] = sh[t] - v;
    if (t == 511) {
        bktoff[NBKT] = sh[511];
        rowst[NN] = sh[511];
    }
}

// ---------------------------------------------------------------------------
// kB v3: fine counting sort with COALESCED srcidx flush -- the same disease
// kA1 v2 just cured (R16). The old scatter wrote srcidx[p] at atomic-cursor
// positions: adjacent lanes hit different ~33-int node runs, so each 4B
// store was its own 64B line transaction (3-6x write amplification on
// 12.8 MB) at 391 blocks with no TLP to hide it. v3 sorts into a 48 KB LDS
// staging array (local cursors = exclusive offsets), then flushes linearly:
// srcidx[obase+i] = lstage[i], consecutive lanes -> consecutive addresses.
// Per-node srcidx SETS unchanged (order within a node was already atomic-
// nondeterministic). LDS 51.2 KB. (R12 fusion-of-agg1 remains refuted.)
__global__ void __launch_bounds__(256) kB_sort(const int* __restrict__ bktcnt,
                                               const int* __restrict__ bktoff,
                                               const int* __restrict__ ebuf,
                                               int* __restrict__ rowst,
                                               int* __restrict__ srcidx) {
    __shared__ int cnt[256];
    __shared__ int tmp[256];
    __shared__ int lstage[BCAP];  // 48 KB: node-sorted src indices
    int b = blockIdx.x, t = threadIdx.x;
    int n = min(bktcnt[b], BCAP);
    int obase = bktoff[b];
    const int* ib = ebuf + b * BCAP;
    const int4* ib4 = (const int4*)ib;
    int nq = n >> 2;
    cnt[t] = 0;
    __syncthreads();
    for (int i = t; i < nq; i += 256) {
        int4 v = ib4[i];
        atomicAdd(&cnt[v.x & 255], 1);
        atomicAdd(&cnt[v.y & 255], 1);
        atomicAdd(&cnt[v.z & 255], 1);
        atomicAdd(&cnt[v.w & 255], 1);
    }
    for (int i = (nq << 2) + t; i < n; i += 256)
        atomicAdd(&cnt[ib[i] & 255], 1);
    __syncthreads();
    int v = cnt[t];
    tmp[t] = v;
    __syncthreads();
    for (int o = 1; o < 256; o <<= 1) {
        int add = (t >= o) ? tmp[t - o] : 0;
        __syncthreads();
        tmp[t] += add;
        __syncthreads();
    }
    int excl = tmp[t] - v;
    int node = (b << 8) + t;
    if (node < NN) rowst[node] = obase + excl;
    cnt[t] = excl;  // LOCAL cursor into the LDS staging array
    __syncthreads();
    // counting-sort scatter into LDS (fast, no global write amplification)
    for (int i = t; i < nq; i += 256) {
        int4 e4 = ib4[i];
        int p;
        p = atomicAdd(&cnt[e4.x & 255], 1); lstage[p] = e4.x >> 8;
        p = atomicAdd(&cnt[e4.y & 255], 1); lstage[p] = e4.y >> 8;
        p = atomicAdd(&cnt[e4.z & 255], 1); lstage[p] = e4.z >> 8;
        p = atomicAdd(&cnt[e4.w & 255], 1); lstage[p] = e4.w >> 8;
    }
    for (int i = (nq << 2) + t; i < n; i += 256) {
        int e = ib[i];
        int p = atomicAdd(&cnt[e & 255], 1);
        lstage[p] = e >> 8;
    }
    __syncthreads();
    // coalesced linear flush
    for (int i = t; i < n; i += 256)
        srcidx[obase + i] = lstage[i];
}

// ---------------------------------------------------------------------------
// Layer-1 aggregation (gather). 16 lanes per node; r2[n] = {T0/s0, T1/s1}.
// (Separate kernel on purpose: 6250 blocks give the TLP that hides the
// x-gather latency -- R12 proved this cannot live inside kB's 391 blocks.)
__global__ void __launch_bounds__(256) k_agg1(const int* __restrict__ rowstart,
                                              const int* __restrict__ srcidx,
                                              const float* __restrict__ x,
                                              const float* __restrict__ c4,
                                              float2* __restrict__ r2) {
    int gtid = blockIdx.x * blockDim.x + threadIdx.x;
    int n = gtid >> 4;
    int lane = gtid & 15;
    if (n >= NN) return;
    float c0 = c4[0], c1 = c4[1], c2 = c4[2], c3 = c4[3];
    float xd = x[n];
    float xdc2 = xd * c2, xdc3 = xd * c3;
    float s0 = 0.f, s1 = 0.f, t0 = 0.f, t1 = 0.f;
    int rs = rowstart[n], re = rowstart[n + 1];
    for (int i = rs + lane; i < re; i += 16) {
        float xs = x[__builtin_nontemporal_load(srcidx + i)];
        float ex0 = __expf(leaky(xs * c0 + xdc2));
        float ex1 = __expf(leaky(xs * c1 + xdc3));
        s0 += ex0;
        s1 += ex1;
        t0 += ex0 * xs;
        t1 += ex1 * xs;
    }
#pragma unroll
    for (int m = 8; m >= 1; m >>= 1) {
        s0 += __shfl_xor(s0, m, 16);
        s1 += __shfl_xor(s1, m, 16);
        t0 += __shfl_xor(t0, m, 16);
        t1 += __shfl_xor(t1, m, 16);
    }
    if (lane == 0) {
        float ex0 = __expf(leaky(xd * (c0 + c2)));
        float ex1 = __expf(leaky(xd * (c1 + c3)));
        s0 += ex0;
        s1 += ex1;
        t0 += ex0 * xd;
        t1 += ex1 * xd;
        r2[n] = make_float2(t0 / (s0 + 1e-16f), t1 / (s1 + 1e-16f));
    }
}

// ---------------------------------------------------------------------------
// k3: per-node layer-1 output -> h2 row (fp8 e4m3, 32 B/row -> 3.2 MB table,
// fits the 4 MB per-XCD L2) + layer-2 attention scalars (f32, full precision).
__global__ void __launch_bounds__(256) k3_node(const float2* __restrict__ r2,
                                               const float* __restrict__ W1,
                                               const float* __restrict__ b1,
                                               const float* __restrict__ W2,
                                               const float* __restrict__ as2,
                                               const float* __restrict__ ad2,
                                               unsigned int* __restrict__ h8,
                                               float2* __restrict__ a2) {
    int n = blockIdx.x * blockDim.x + threadIdx.x;
    if (n >= NN) return;
    float2 r = r2[n];
    float h2[32];
#pragma unroll
    for (int c = 0; c < 32; ++c) h2[c] = 0.f;
    for (int j = 0; j < 64; ++j) {
        float o = W1[j] * (j < 32 ? r.x : r.y) + b1[j];
        o = fmaxf(o, 0.f);
#pragma unroll
        for (int c = 0; c < 32; ++c) h2[c] += o * W2[j * 32 + c];
    }
    float asum = 0.f, adsum = 0.f;
#pragma unroll
    for (int c = 0; c < 32; ++c) {
        asum += h2[c] * as2[c];
        adsum += h2[c] * ad2[c];
    }
    a2[n] = make_float2(asum, adsum);
    unsigned int w[8];
#pragma unroll
    for (int q = 0; q < 8; ++q) {
        int v = __builtin_amdgcn_cvt_pk_fp8_f32(h2[q * 4 + 0], h2[q * 4 + 1], 0, false);
        v = __builtin_amdgcn_cvt_pk_fp8_f32(h2[q * 4 + 2], h2[q * 4 + 3], v, true);
        w[q] = (unsigned int)v;
    }
    uint4* hg = (uint4*)(h8 + (size_t)n * 8);
    hg[0] = make_uint4(w[0], w[1], w[2], w[3]);
    hg[1] = make_uint4(w[4], w[5], w[6], w[7]);
}

// ---------------------------------------------------------------------------
// Layer-2 aggregation (gather). 32 lanes per node, lane = channel.
// v2 (kept): latency-hiding restructure (LDS-staged off/ex broadcast,
// 32-deep MLP, padded batches -> no divergent tail). R14 counters: 52.8 us,
// VALUBusy 57%, occupancy 56% -- issue-bound, acceptable.
__global__ void __launch_bounds__(256) k_agg2(const int* __restrict__ rowstart,
                                              const int* __restrict__ srcidx,
                                              const unsigned char* __restrict__ h8,
                                              const float2* __restrict__ a2,
                                              const float* __restrict__ b2,
                                              unsigned short* __restrict__ embq) {
    __shared__ int loff[256];
    __shared__ float lex[256];
    int tid = threadIdx.x;
    int gtid = blockIdx.x * 256 + tid;
    int n = gtid >> 5;
    int c = gtid & 31;
    if (n >= NN) return;
    int wbase = tid & ~31;  // this 32-lane group's LDS slot base
    float2 an = a2[n];
    float adn = an.y;
    float exn = __expf(leaky(an.x + adn));
    float u = exn * __builtin_amdgcn_cvt_f32_fp8(h8[((unsigned)n << 5) + c], 0);
    float lsum = 0.f;  // per-lane partial of sum(ex)
    int rs = rowstart[n], re = rowstart[n + 1];
    for (int base = rs; base < re; base += 32) {
        int cnt = re - base;
        int off = 0;
        float exj = 0.f;
        if (c < cnt) {
            int sjv = __builtin_nontemporal_load(srcidx + base + c);
            off = sjv << 5;
            float2 asrc = a2[sjv];  // issued early; latency overlapped below
            exj = __expf(leaky(asrc.x + adn));
            lsum += exj;
        }
        // stage offsets, then launch ALL 32 h8 loads (they only need srcidx)
        loff[tid] = off;
        asm volatile("s_waitcnt lgkmcnt(0)" ::: "memory");
        int4 ov[8];
#pragma unroll
        for (int q = 0; q < 8; ++q) ov[q] = ((const int4*)(loff + wbase))[q];
        unsigned int hb[32];
#pragma unroll
        for (int q = 0; q < 8; ++q) {
            hb[4 * q + 0] = h8[ov[q].x + c];
            hb[4 * q + 1] = h8[ov[q].y + c];
            hb[4 * q + 2] = h8[ov[q].z + c];
            hb[4 * q + 3] = h8[ov[q].w + c];
        }
        // stage ex (ready once the a2 gather + exp completes)
        lex[tid] = exj;
        asm volatile("s_waitcnt lgkmcnt(0)" ::: "memory");
#pragma unroll
        for (int q = 0; q < 8; ++q) {
            float4 ev = ((const float4*)(lex + wbase))[q];
            u += ev.x * __builtin_amdgcn_cvt_f32_fp8(hb[4 * q + 0], 0);
            u += ev.y * __builtin_amdgcn_cvt_f32_fp8(hb[4 * q + 1], 0);
            u += ev.z * __builtin_amdgcn_cvt_f32_fp8(hb[4 * q + 2], 0);
            u += ev.w * __builtin_amdgcn_cvt_f32_fp8(hb[4 * q + 3], 0);
        }
    }
#pragma unroll
    for (int m = 16; m >= 1; m >>= 1) lsum += __shfl_xor(lsum, m, 32);
    float ssum = lsum + exn;
    embq[((unsigned)n << 5) + c] = (unsigned short)f2bf(u / (ssum + 1e-16f) + b2[c]);
}

// ---------------------------------------------------------------------------
// k6: MFMA edge scorer.
// v6 (best measured: 78.4 us fast-session / 96 us R16's slow session --
// uniform rate scaling with identical traffic = board/clock variance).
// Concurrency bracket complete (R5/R6/R11): v6 is argmax.
__global__ void __launch_bounds__(256) k6_mfma(const int* __restrict__ ei,
                                               const float* __restrict__ ea,
                                               const unsigned short* __restrict__ embq,
                                               const float* __restrict__ Wm1,
                                               const float* __restrict__ bm1,
                                               const float* __restrict__ Wm2,
                                               const float* __restrict__ bm2,
                                               const float* __restrict__ Wm3,
                                               const float* __restrict__ bm3,
                                               float* __restrict__ out) {
    __shared__ unsigned short ldsq[4][4 * 640];  // 4 waves x 4 tiles (bf16 ph1 out, f32 ph2 reuse)
    int tid = threadIdx.x;
    int wave = tid >> 6, lane = tid & 63;
    int m = lane & 15, quad = lane >> 4;
    unsigned short* wl = ldsq[wave];
    float* wz = (float*)wl;  // phase-2 alias of the same 5120-B wave zone

    // weight fragments; layer-1 tile t column m = channel 2m+t
    bf16x8 B1[3][2];
#pragma unroll
    for (int c = 0; c < 3; ++c) {
#pragma unroll
        for (int t = 0; t < 2; ++t) {
            bf16x8 v;
#pragma unroll
            for (int j = 0; j < 8; ++j) {
                int kk = c * 32 + quad * 8 + j;
                float w = (kk < 68) ? Wm1[kk * 32 + 2 * m + t] : 0.f;
                v[j] = (short)f2bf(w);
            }
            B1[c][t] = v;
        }
    }
    bf16x8 B2;
#pragma unroll
    for (int j = 0; j < 8; ++j)
        B2[j] = (short)f2bf(Wm2[(quad * 8 + j) * 16 + m]);
    float bl = bm1[2 * m], bh = bm1[2 * m + 1];
    float b2v = bm2[m], w3v = Wm3[m], b3 = bm3[0];

    int gw = blockIdx.x * 4 + wave;

    // double-buffered pipeline state
    int s2[2][4], d2[2][4];
    f32x4 ev2[2][4];
    bf16x8 A0[2][4], A1[2][4];

    auto LOADIDX = [&](int b, int ii) {
#pragma unroll
        for (int u = 0; u < 4; ++u) {
            int e = (gw * 16 + ii * 4) * 16 + u * 16 + m;
            s2[b][u] = __builtin_nontemporal_load(ei + e);
            d2[b][u] = __builtin_nontemporal_load(ei + NE + e);
            if (quad == 0)
                ev2[b][u] = __builtin_nontemporal_load((const f32x4*)ea + e);
        }
    };
    auto GATHER = [&](int b) {
#pragma unroll
        for (int u = 0; u < 4; ++u) {
            A0[b][u] = *(const bf16x8*)(embq + (((unsigned)s2[b][u] << 5) + quad * 8));
            A1[b][u] = *(const bf16x8*)(embq + (((unsigned)d2[b][u] << 5) + quad * 8));
        }
    };

    LOADIDX(0, 0);
    GATHER(0);
    LOADIDX(1, 1);

#pragma unroll
    for (int ii = 0; ii < 4; ++ii) {
        const int b = ii & 1;
        int eb0 = (gw * 16 + ii * 4) * 16;  // 64 consecutive edges
        // ---- phase 1: waits on GATHER(b) issued one iteration ago ----
#pragma unroll
        for (int u = 0; u < 4; ++u) {
            bf16x8 z = {0, 0, 0, 0, 0, 0, 0, 0};
            if (quad == 0) {
                f32x4 av = ev2[b][u];
                z[0] = (short)f2bf(av[0]);
                z[1] = (short)f2bf(av[1]);
                z[2] = (short)f2bf(av[2]);
                z[3] = (short)f2bf(av[3]);
            }
            f32x4 accL = {bl, bl, bl, bl};  // bias folded into acc init
            f32x4 accH = {bh, bh, bh, bh};
            accL = __builtin_amdgcn_mfma_f32_16x16x32_bf16(A0[b][u], B1[0][0], accL, 0, 0, 0);
            accH = __builtin_amdgcn_mfma_f32_16x16x32_bf16(A0[b][u], B1[0][1], accH, 0, 0, 0);
            accL = __builtin_amdgcn_mfma_f32_16x16x32_bf16(A1[b][u], B1[1][0], accL, 0, 0, 0);
            accH = __builtin_amdgcn_mfma_f32_16x16x32_bf16(A1[b][u], B1[1][1], accH, 0, 0, 0);
            accL = __builtin_amdgcn_mfma_f32_16x16x32_bf16(z, B1[2][0], accL, 0, 0, 0);
            accH = __builtin_amdgcn_mfma_f32_16x16x32_bf16(z, B1[2][1], accH, 0, 0, 0);
#pragma unroll
            for (int r = 0; r < 4; ++r) {
                int row = quad * 4 + r;
                unsigned int uL = __float_as_uint(fmaxf(accL[r], 0.f)) + 0x8000u;
                unsigned int uH = __float_as_uint(fmaxf(accH[r], 0.f)) + 0x8000u;
                unsigned int packed = __builtin_amdgcn_perm(uH, uL, 0x07060302);
                *(unsigned int*)(wl + u * 640 + row * 40 + 2 * m) = packed;
            }
        }
        // ---- issue next group's gathers / next-next index loads ----
        if (ii < 3) GATHER(b ^ 1);      // idx loaded 1-2 iterations ago
        if (ii < 2) LOADIDX(b, ii + 2); // buffer b's idx/frags just consumed
        asm volatile("s_waitcnt lgkmcnt(0)" ::: "memory");
        // ---- phase 2 (latency of the above loads hides under this) ----
#pragma unroll
        for (int u = 0; u < 4; ++u) {
            // read tile u (last use of its bf16 contents) ...
            bf16x8 aq = *(const bf16x8*)(wl + u * 640 + m * 40 + quad * 8);
            f32x4 accO = {b2v, b2v, b2v, b2v};  // layer-2 bias folded
            accO = __builtin_amdgcn_mfma_f32_16x16x32_bf16(aq, B2, accO, 0, 0, 0);
            // ... then overwrite tile u with the f32 edge x channel transpose
#pragma unroll
            for (int r = 0; r < 4; ++r) {
                int edge = u * 16 + quad * 4 + r;
                wz[edge * 20 + m] = fmaxf(accO[r], 0.f) * w3v;
            }
        }
        asm volatile("s_waitcnt lgkmcnt(0)" ::: "memory");
        // lane owns edge `lane`: sum 16 ch, sigmoid, coalesced store
        {
            f32x4 p0 = *(const f32x4*)(wz + lane * 20 + 0);
            f32x4 p1 = *(const f32x4*)(wz + lane * 20 + 4);
            f32x4 p2 = *(const f32x4*)(wz + lane * 20 + 8);
            f32x4 p3 = *(const f32x4*)(wz + lane * 20 + 12);
            float sum = ((p0[0] + p0[1]) + (p0[2] + p0[3])) +
                        ((p1[0] + p1[1]) + (p1[2] + p1[3])) +
                        ((p2[0] + p2[1]) + (p2[2] + p2[3])) +
                        ((p3[0] + p3[1]) + (p3[2] + p3[3]));
            float sc = 1.f / (1.f + __expf(-(sum + b3)));
            __builtin_nontemporal_store(sc, out + eb0 + lane);
        }
        asm volatile("" ::: "memory");
    }
}

// ---------------------------------------------------------------------------
extern "C" void kernel_launch(void* const* d_in, const int* in_sizes, int n_in,
                              void* d_out, int out_size, void* d_ws, size_t ws_size,
                              hipStream_t stream) {
    const float* x   = (const float*)d_in[0];
    const int* ei    = (const int*)d_in[1];
    const float* ea  = (const float*)d_in[2];
    const float* W1  = (const float*)d_in[3];
    const float* as1 = (const float*)d_in[4];
    const float* ad1 = (const float*)d_in[5];
    const float* b1  = (const float*)d_in[6];
    const float* W2  = (const float*)d_in[7];
    const float* as2 = (const float*)d_in[8];
    const float* ad2 = (const float*)d_in[9];
    const float* b2  = (const float*)d_in[10];
    const float* Wm1 = (const float*)d_in[11];
    const float* bm1 = (const float*)d_in[12];
    const float* Wm2 = (const float*)d_in[13];
    const float* bm2 = (const float*)d_in[14];
    const float* Wm3 = (const float*)d_in[15];
    const float* bm3 = (const float*)d_in[16];
    float* out = (float*)d_out;

    // workspace layout (bytes), total ~40.4 MB
    char* ws = (char*)d_ws;
    float* c4      = (float*)(ws + 0);          // 16 B
    int*   bktcnt  = (int*)  (ws + 256);        // NBKT*4 (cursor -> final counts)
    int*   bktoff  = (int*)  (ws + 2048);       // (NBKT+1)*4
    int*   rowst   = (int*)  (ws + 5632);       // (NN+1)*4
    float* r2      = (float*)(ws + 405760);     // NN*8
    float* a2      = (float*)(ws + 1205760);    // NN*8
    int*   ebufP   = (int*)  (ws + 2005760);    // NBKT*BCAP*4 = 19.2 MB (padded)
    int*   srcidx  = (int*)  (ws + 21224192);   // NE*4 = 12.8 MB
    unsigned char* h8    = (unsigned char*)ebufP;            // NN*32 fp8 = 3.2 MB (after kB)
    unsigned short* embq = (unsigned short*)(ws + 34024192); // NN*32*2 = 6.4 MB

    const int NB = (NN + 255) / 256;
    const int TB = (NE + TILE_E - 1) / TILE_E;  // 391 at TILE_E=8192

    hipMemsetAsync(bktcnt, 0, NBKT * sizeof(int), stream);
    hipLaunchKernelGGL(kA1_part, dim3(TB), dim3(256), 0, stream, ei, bktcnt, ebufP);
    hipLaunchKernelGGL(kscan, dim3(1), dim3(512), 0, stream, bktcnt, bktoff, rowst,
                       W1, as1, ad1, c4);
    hipLaunchKernelGGL(kB_sort, dim3(NBKT), dim3(256), 0, stream, bktcnt, bktoff, ebufP,
                       rowst, srcidx);
    hipLaunchKernelGGL(k_agg1, dim3((NN * 16 + 255) / 256), dim3(256), 0, stream,
                       rowst, srcidx, x, c4, (float2*)r2);
    hipLaunchKernelGGL(k3_node, dim3(NB), dim3(256), 0, stream, (float2*)r2, W1, b1, W2,
                       as2, ad2, (unsigned int*)h8, (float2*)a2);
    hipLaunchKernelGGL(k_agg2, dim3((NN * 32 + 255) / 256), dim3(256), 0, stream,
                       rowst, srcidx, h8, (float2*)a2, b2, embq);
    hipLaunchKernelGGL(k6_mfma, dim3(K6_BLOCKS), dim3(256), 0, stream, ei, ea, embq,
                       Wm1, bm1, Wm2, bm2, Wm3, bm3, out);
}